// Round 1
// baseline (847.382 us; speedup 1.0000x reference)
//
#include <hip/hip_runtime.h>
#include <cstdint>
#include <cstddef>

// ---------------- small utility kernels ----------------

__global__ void k_zero(int* __restrict__ p, int n) {
    int i = blockIdx.x * blockDim.x + threadIdx.x;
    if (i < n) p[i] = 0;
}

__global__ void k_deg(const int* __restrict__ dst, int* __restrict__ deg, int E) {
    int e = blockIdx.x * blockDim.x + threadIdx.x;
    if (e < E) atomicAdd(&deg[dst[e]], 1);
}

__global__ void k_dinv(const int* __restrict__ deg, float* __restrict__ dinv, int N) {
    int i = blockIdx.x * blockDim.x + threadIdx.x;
    if (i < N) dinv[i] = rsqrtf((float)(deg[i] + 1));   // +1 = self-loop
}

// ---------------- exclusive scan (3 kernels) ----------------

__global__ void k_scan1(const int* __restrict__ deg, int* __restrict__ rowptr,
                        int* __restrict__ bsum, int N) {
    __shared__ int s[256];
    int t = threadIdx.x;
    int i = blockIdx.x * 256 + t;
    int v = (i < N) ? deg[i] : 0;
    s[t] = v;
    __syncthreads();
    for (int off = 1; off < 256; off <<= 1) {
        int add = (t >= off) ? s[t - off] : 0;
        __syncthreads();
        s[t] += add;
        __syncthreads();
    }
    if (i < N) rowptr[i] = s[t] - v;           // exclusive within block
    if (t == 255) bsum[blockIdx.x] = s[255];   // block total
}

__global__ void k_scan2(int* __restrict__ bsum, int nb) {
    __shared__ int s[512];
    int t = threadIdx.x;
    int v = (t < nb) ? bsum[t] : 0;
    s[t] = v;
    __syncthreads();
    for (int off = 1; off < 512; off <<= 1) {
        int add = (t >= off) ? s[t - off] : 0;
        __syncthreads();
        s[t] += add;
        __syncthreads();
    }
    if (t < nb) bsum[t] = s[t] - v;            // exclusive block offsets
}

__global__ void k_scan3(int* __restrict__ rowptr, const int* __restrict__ bsum,
                        int* __restrict__ cursor, int N, int E) {
    int i = blockIdx.x * 256 + threadIdx.x;
    if (i < N) {
        rowptr[i] += bsum[blockIdx.x];
        cursor[i] = 0;
    }
    if (i == 0) rowptr[N] = E;
}

__global__ void k_scatter(const int* __restrict__ src, const int* __restrict__ dst,
                          const int* __restrict__ rowptr, int* __restrict__ cursor,
                          int* __restrict__ csr_src, int E) {
    int e = blockIdx.x * blockDim.x + threadIdx.x;
    if (e < E) {
        int d = dst[e];
        int pos = atomicAdd(&cursor[d], 1);
        csr_src[rowptr[d] + pos] = src[e];
    }
}

// ---------------- GEMM1: h1[N,64] = x[N,512] @ W1[512,64] ----------------
// 64 rows x 64 cols per block, 256 threads, 4x4 micro-tile, K-chunks of 32.

__global__ __launch_bounds__(256) void k_gemm1(const float* __restrict__ x,
                                               const float* __restrict__ W1,
                                               float* __restrict__ h1, int N) {
    __shared__ float xsT[32][68];   // [kk][row], stride 68 keeps float4 aligned (272B)
    __shared__ float ws[32][64];    // [kk][col]
    int t = threadIdx.x;
    int tc = t & 15;        // col group (4 cols)
    int tr = t >> 4;        // row group (4 rows)
    int row0 = blockIdx.x * 64;

    float acc[4][4] = {{0.f}};

    int lr  = t >> 2;        // staging row 0..63
    int lkq = (t & 3) * 8;   // staging k offset (8 floats)

    for (int k0 = 0; k0 < 512; k0 += 32) {
        // stage x chunk (transposed into LDS)
        {
            int gr = row0 + lr;
            float4 v0 = {0.f, 0.f, 0.f, 0.f}, v1 = {0.f, 0.f, 0.f, 0.f};
            if (gr < N) {
                const float* p = x + (size_t)gr * 512 + k0 + lkq;
                v0 = *(const float4*)p;
                v1 = *(const float4*)(p + 4);
            }
            xsT[lkq + 0][lr] = v0.x; xsT[lkq + 1][lr] = v0.y;
            xsT[lkq + 2][lr] = v0.z; xsT[lkq + 3][lr] = v0.w;
            xsT[lkq + 4][lr] = v1.x; xsT[lkq + 5][lr] = v1.y;
            xsT[lkq + 6][lr] = v1.z; xsT[lkq + 7][lr] = v1.w;
        }
        // stage W1 chunk (straight copy, 2048 floats)
        {
            const float* p = W1 + (size_t)k0 * 64 + t * 8;
            float4 v0 = *(const float4*)p;
            float4 v1 = *(const float4*)(p + 4);
            int kk = (t * 8) >> 6;
            int cc = (t * 8) & 63;
            *(float4*)&ws[kk][cc]     = v0;
            *(float4*)&ws[kk][cc + 4] = v1;
        }
        __syncthreads();

#pragma unroll
        for (int kk = 0; kk < 32; ++kk) {
            float4 a = *(const float4*)&xsT[kk][tr * 4];
            float4 b = *(const float4*)&ws[kk][tc * 4];
            acc[0][0] += a.x * b.x; acc[0][1] += a.x * b.y;
            acc[0][2] += a.x * b.z; acc[0][3] += a.x * b.w;
            acc[1][0] += a.y * b.x; acc[1][1] += a.y * b.y;
            acc[1][2] += a.y * b.z; acc[1][3] += a.y * b.w;
            acc[2][0] += a.z * b.x; acc[2][1] += a.z * b.y;
            acc[2][2] += a.z * b.z; acc[2][3] += a.z * b.w;
            acc[3][0] += a.w * b.x; acc[3][1] += a.w * b.y;
            acc[3][2] += a.w * b.z; acc[3][3] += a.w * b.w;
        }
        __syncthreads();
    }

#pragma unroll
    for (int r = 0; r < 4; ++r) {
        int gr = row0 + tr * 4 + r;
        if (gr < N) {
            float4 v = {acc[r][0], acc[r][1], acc[r][2], acc[r][3]};
            *(float4*)&h1[(size_t)gr * 64 + tc * 4] = v;
        }
    }
}

// ---------------- agg1: out1 = relu(dinv[n]*(sum dinv[s]*h1[s] + dinv[n]*h1[n]) + b1)
// one wave per node, lane = column (H=64)

__global__ __launch_bounds__(256) void k_agg1(const float* __restrict__ h1,
                                              const int* __restrict__ rowptr,
                                              const int* __restrict__ csr_src,
                                              const float* __restrict__ dinv,
                                              const float* __restrict__ b1,
                                              float* __restrict__ out1, int N) {
    int wid = threadIdx.x >> 6;
    int lane = threadIdx.x & 63;
    int n = blockIdx.x * 4 + wid;
    if (n >= N) return;
    int start = rowptr[n];
    int cnt = rowptr[n + 1] - start;

    float acc = 0.f;
    for (int base = 0; base < cnt; base += 64) {
        int m = min(64, cnt - base);
        int sv = 0; float wv = 0.f;
        if (lane < m) {
            sv = csr_src[start + base + lane];
            wv = dinv[sv];
        }
#pragma unroll 4
        for (int i = 0; i < m; ++i) {
            int   s = __shfl(sv, i, 64);
            float w = __shfl(wv, i, 64);
            acc += w * h1[(size_t)s * 64 + lane];
        }
    }
    float dn = dinv[n];
    acc = dn * (acc + dn * h1[(size_t)n * 64 + lane]) + b1[lane];
    out1[(size_t)n * 64 + lane] = fmaxf(acc, 0.f);
}

// ---------------- GEMM2: h2[N,8] = out1[N,64] @ W2[64,8] ----------------

__global__ __launch_bounds__(256) void k_gemm2(const float* __restrict__ out1,
                                               const float* __restrict__ W2,
                                               float* __restrict__ h2, int N) {
    __shared__ float w[512];
    int t = threadIdx.x;
    w[t] = W2[t];
    w[t + 256] = W2[t + 256];
    __syncthreads();

    int tid = blockIdx.x * 256 + t;
    int n = tid >> 3, c = tid & 7;
    if (n >= N) return;
    const float* row = out1 + (size_t)n * 64;
    float acc = 0.f;
#pragma unroll
    for (int k4 = 0; k4 < 64; k4 += 4) {
        float4 v = *(const float4*)(row + k4);
        acc += v.x * w[(k4 + 0) * 8 + c];
        acc += v.y * w[(k4 + 1) * 8 + c];
        acc += v.z * w[(k4 + 2) * 8 + c];
        acc += v.w * w[(k4 + 3) * 8 + c];
    }
    h2[(size_t)n * 8 + c] = acc;
}

// ---------------- agg2: out = dinv[n]*(sum dinv[s]*h2[s] + dinv[n]*h2[n]) + b2
// one wave per node: 8 neighbor sub-groups x 8 cols, butterfly reduce.

__global__ __launch_bounds__(256) void k_agg2(const float* __restrict__ h2,
                                              const int* __restrict__ rowptr,
                                              const int* __restrict__ csr_src,
                                              const float* __restrict__ dinv,
                                              const float* __restrict__ b2,
                                              float* __restrict__ out, int N) {
    int wid = threadIdx.x >> 6;
    int lane = threadIdx.x & 63;
    int n = blockIdx.x * 4 + wid;
    if (n >= N) return;
    int start = rowptr[n];
    int cnt = rowptr[n + 1] - start;
    int c = lane & 7;
    int ii = lane >> 3;

    float acc = 0.f;
    for (int base = 0; base < cnt; base += 8) {
        int i = base + ii;
        if (i < cnt) {
            int s = csr_src[start + i];
            acc += dinv[s] * h2[(size_t)s * 8 + c];
        }
    }
    acc += __shfl_xor(acc, 8, 64);
    acc += __shfl_xor(acc, 16, 64);
    acc += __shfl_xor(acc, 32, 64);

    if (lane < 8) {
        float dn = dinv[n];
        out[(size_t)n * 8 + lane] =
            dn * (acc + dn * h2[(size_t)n * 8 + lane]) + b2[lane];
    }
}

// ---------------- host launcher ----------------

extern "C" void kernel_launch(void* const* d_in, const int* in_sizes, int n_in,
                              void* d_out, int out_size, void* d_ws, size_t ws_size,
                              hipStream_t stream) {
    const float* x  = (const float*)d_in[0];
    const int*   ei = (const int*)d_in[1];
    const float* W1 = (const float*)d_in[2];
    const float* b1 = (const float*)d_in[3];
    const float* W2 = (const float*)d_in[4];
    const float* b2 = (const float*)d_in[5];
    float* out = (float*)d_out;

    const int H   = in_sizes[3];            // 64
    const int FIN = in_sizes[2] / H;        // 512
    const int N   = in_sizes[0] / FIN;      // 100000
    const int E   = in_sizes[1] / 2;        // 3200000
    const int* srcA = ei;
    const int* dstA = ei + E;

    char* ws = (char*)d_ws;
    size_t off = 0;
    auto alloc = [&](size_t bytes) -> void* {
        void* p = ws + off;
        off += (bytes + 255) & ~(size_t)255;
        return p;
    };
    int*   deg     = (int*)alloc((size_t)N * 4);
    float* dinv    = (float*)alloc((size_t)N * 4);
    int*   rowptr  = (int*)alloc((size_t)(N + 1) * 4);
    int*   cursor  = (int*)alloc((size_t)N * 4);
    int*   bsum    = (int*)alloc(4096);
    int*   csr_src = (int*)alloc((size_t)E * 4);
    float* h1      = (float*)alloc((size_t)N * 64 * 4);
    float* out1    = (float*)alloc((size_t)N * 64 * 4);
    float* h2      = (float*)alloc((size_t)N * 8 * 4);
    (void)ws_size; (void)n_in; (void)out_size;

    int nb = (N + 255) / 256;    // scan blocks (391)

    k_zero   <<<nb, 256, 0, stream>>>(deg, N);
    k_deg    <<<(E + 255) / 256, 256, 0, stream>>>(dstA, deg, E);
    k_dinv   <<<nb, 256, 0, stream>>>(deg, dinv, N);
    k_scan1  <<<nb, 256, 0, stream>>>(deg, rowptr, bsum, N);
    k_scan2  <<<1, 512, 0, stream>>>(bsum, nb);
    k_scan3  <<<nb, 256, 0, stream>>>(rowptr, bsum, cursor, N, E);
    k_scatter<<<(E + 255) / 256, 256, 0, stream>>>(srcA, dstA, rowptr, cursor, csr_src, E);
    k_gemm1  <<<(N + 63) / 64, 256, 0, stream>>>(x, W1, h1, N);
    k_agg1   <<<(N + 3) / 4, 256, 0, stream>>>(h1, rowptr, csr_src, dinv, b1, out1, N);
    k_gemm2  <<<(N * 8 + 255) / 256, 256, 0, stream>>>(out1, W2, h2, N);
    k_agg2   <<<(N + 3) / 4, 256, 0, stream>>>(h2, rowptr, csr_src, dinv, b2, out, N);
}

// Round 2
// 756.249 us; speedup vs baseline: 1.1205x; 1.1205x over previous
//
#include <hip/hip_runtime.h>
#include <cstdint>
#include <cstddef>

// ---------------- small utility kernels ----------------

__global__ void k_zero(int* __restrict__ p, int n) {
    int i = blockIdx.x * blockDim.x + threadIdx.x;
    if (i < n) p[i] = 0;
}

__global__ void k_deg(const int* __restrict__ dst, int* __restrict__ deg, int E) {
    int e = blockIdx.x * blockDim.x + threadIdx.x;
    if (e < E) atomicAdd(&deg[dst[e]], 1);
}

// ---------------- exclusive scan (3 kernels) ----------------

__global__ void k_scan1(const int* __restrict__ deg, int* __restrict__ rowptr,
                        int* __restrict__ bsum, int N) {
    __shared__ int s[256];
    int t = threadIdx.x;
    int i = blockIdx.x * 256 + t;
    int v = (i < N) ? deg[i] : 0;
    s[t] = v;
    __syncthreads();
    for (int off = 1; off < 256; off <<= 1) {
        int add = (t >= off) ? s[t - off] : 0;
        __syncthreads();
        s[t] += add;
        __syncthreads();
    }
    if (i < N) rowptr[i] = s[t] - v;           // exclusive within block
    if (t == 255) bsum[blockIdx.x] = s[255];   // block total
}

__global__ void k_scan2(int* __restrict__ bsum, int nb) {
    __shared__ int s[512];
    int t = threadIdx.x;
    int v = (t < nb) ? bsum[t] : 0;
    s[t] = v;
    __syncthreads();
    for (int off = 1; off < 512; off <<= 1) {
        int add = (t >= off) ? s[t - off] : 0;
        __syncthreads();
        s[t] += add;
        __syncthreads();
    }
    if (t < nb) bsum[t] = s[t] - v;            // exclusive block offsets
}

// scan3 + dinv + cursor init fused
__global__ void k_scan3(int* __restrict__ rowptr, const int* __restrict__ bsum,
                        int* __restrict__ cursor, const int* __restrict__ deg,
                        float* __restrict__ dinv, int N, int E) {
    int i = blockIdx.x * 256 + threadIdx.x;
    if (i < N) {
        rowptr[i] += bsum[blockIdx.x];
        cursor[i] = 0;
        dinv[i] = rsqrtf((float)(deg[i] + 1));   // +1 = self-loop
    }
    if (i == 0) rowptr[N] = E;
}

// scatter edges into CSR; store (src, dinv[src]) pairs so the agg kernels
// never gather dinv at random.
__global__ void k_scatter(const int* __restrict__ src, const int* __restrict__ dst,
                          const int* __restrict__ rowptr, int* __restrict__ cursor,
                          const float* __restrict__ dinv, int2* __restrict__ csr_sw,
                          int E) {
    int e = blockIdx.x * blockDim.x + threadIdx.x;
    if (e < E) {
        int d = dst[e];
        int s = src[e];
        int pos = atomicAdd(&cursor[d], 1);
        int2 q;
        q.x = s;
        q.y = __float_as_int(dinv[s]);
        csr_sw[rowptr[d] + pos] = q;
    }
}

// ---------------- GEMM1: h1[N,64] = x[N,512] @ W1[512,64] ----------------
// 64 rows x 64 cols per block, 256 threads, 4x4 micro-tile, K-chunks of 32.

__global__ __launch_bounds__(256) void k_gemm1(const float* __restrict__ x,
                                               const float* __restrict__ W1,
                                               float* __restrict__ h1, int N) {
    __shared__ float xsT[32][68];   // [kk][row], stride 68 keeps float4 aligned
    __shared__ float ws[32][64];    // [kk][col]
    int t = threadIdx.x;
    int tc = t & 15;        // col group (4 cols)
    int tr = t >> 4;        // row group (4 rows)
    int row0 = blockIdx.x * 64;

    float acc[4][4] = {{0.f}};

    int lr  = t >> 2;        // staging row 0..63
    int lkq = (t & 3) * 8;   // staging k offset (8 floats)

    for (int k0 = 0; k0 < 512; k0 += 32) {
        {
            int gr = row0 + lr;
            float4 v0 = {0.f, 0.f, 0.f, 0.f}, v1 = {0.f, 0.f, 0.f, 0.f};
            if (gr < N) {
                const float* p = x + (size_t)gr * 512 + k0 + lkq;
                v0 = *(const float4*)p;
                v1 = *(const float4*)(p + 4);
            }
            xsT[lkq + 0][lr] = v0.x; xsT[lkq + 1][lr] = v0.y;
            xsT[lkq + 2][lr] = v0.z; xsT[lkq + 3][lr] = v0.w;
            xsT[lkq + 4][lr] = v1.x; xsT[lkq + 5][lr] = v1.y;
            xsT[lkq + 6][lr] = v1.z; xsT[lkq + 7][lr] = v1.w;
        }
        {
            const float* p = W1 + (size_t)k0 * 64 + t * 8;
            float4 v0 = *(const float4*)p;
            float4 v1 = *(const float4*)(p + 4);
            int kk = (t * 8) >> 6;
            int cc = (t * 8) & 63;
            *(float4*)&ws[kk][cc]     = v0;
            *(float4*)&ws[kk][cc + 4] = v1;
        }
        __syncthreads();

#pragma unroll
        for (int kk = 0; kk < 32; ++kk) {
            float4 a = *(const float4*)&xsT[kk][tr * 4];
            float4 b = *(const float4*)&ws[kk][tc * 4];
            acc[0][0] += a.x * b.x; acc[0][1] += a.x * b.y;
            acc[0][2] += a.x * b.z; acc[0][3] += a.x * b.w;
            acc[1][0] += a.y * b.x; acc[1][1] += a.y * b.y;
            acc[1][2] += a.y * b.z; acc[1][3] += a.y * b.w;
            acc[2][0] += a.z * b.x; acc[2][1] += a.z * b.y;
            acc[2][2] += a.z * b.z; acc[2][3] += a.z * b.w;
            acc[3][0] += a.w * b.x; acc[3][1] += a.w * b.y;
            acc[3][2] += a.w * b.z; acc[3][3] += a.w * b.w;
        }
        __syncthreads();
    }

#pragma unroll
    for (int r = 0; r < 4; ++r) {
        int gr = row0 + tr * 4 + r;
        if (gr < N) {
            float4 v = {acc[r][0], acc[r][1], acc[r][2], acc[r][3]};
            *(float4*)&h1[(size_t)gr * 64 + tc * 4] = v;
        }
    }
}

// ---------------- agg1 + GEMM2 fused ----------------
// one wave per node, lane = column (H=64).
// r = relu(dinv[n]*(sum_s w_s*h1[s] + dinv[n]*h1[n]) + b1)   (in regs, 1/lane)
// h2[n,c] = sum_k r[k]*W2[k,c]  via 8 butterfly reductions, compile-time select.

__global__ __launch_bounds__(256) void k_agg1(const float* __restrict__ h1,
                                              const int* __restrict__ rowptr,
                                              const int2* __restrict__ csr_sw,
                                              const float* __restrict__ dinv,
                                              const float* __restrict__ b1,
                                              const float* __restrict__ W2,
                                              float* __restrict__ h2, int N) {
    int wid = threadIdx.x >> 6;
    int lane = threadIdx.x & 63;
    int n = blockIdx.x * 4 + wid;
    if (n >= N) return;

    // hoisted loads (overlap with neighbor gathers)
    float w2r[8];
#pragma unroll
    for (int c = 0; c < 8; ++c) w2r[c] = W2[lane * 8 + c];
    float bias = b1[lane];
    float dn   = dinv[n];
    float self = h1[(size_t)n * 64 + lane];

    int start = __builtin_amdgcn_readfirstlane(rowptr[n]);
    int cnt   = __builtin_amdgcn_readfirstlane(rowptr[n + 1]) - start;
    const int2* qp = csr_sw + start;

    float acc0 = 0.f, acc1 = 0.f;
    int i = 0;
    for (; i + 8 <= cnt; i += 8) {
        int2 q0 = qp[i + 0]; int2 q1 = qp[i + 1];
        int2 q2 = qp[i + 2]; int2 q3 = qp[i + 3];
        int2 q4 = qp[i + 4]; int2 q5 = qp[i + 5];
        int2 q6 = qp[i + 6]; int2 q7 = qp[i + 7];
        float v0 = h1[(size_t)q0.x * 64 + lane];
        float v1 = h1[(size_t)q1.x * 64 + lane];
        float v2 = h1[(size_t)q2.x * 64 + lane];
        float v3 = h1[(size_t)q3.x * 64 + lane];
        float v4 = h1[(size_t)q4.x * 64 + lane];
        float v5 = h1[(size_t)q5.x * 64 + lane];
        float v6 = h1[(size_t)q6.x * 64 + lane];
        float v7 = h1[(size_t)q7.x * 64 + lane];
        acc0 = fmaf(__int_as_float(q0.y), v0, acc0);
        acc1 = fmaf(__int_as_float(q1.y), v1, acc1);
        acc0 = fmaf(__int_as_float(q2.y), v2, acc0);
        acc1 = fmaf(__int_as_float(q3.y), v3, acc1);
        acc0 = fmaf(__int_as_float(q4.y), v4, acc0);
        acc1 = fmaf(__int_as_float(q5.y), v5, acc1);
        acc0 = fmaf(__int_as_float(q6.y), v6, acc0);
        acc1 = fmaf(__int_as_float(q7.y), v7, acc1);
    }
    for (; i < cnt; ++i) {
        int2 q = qp[i];
        acc0 = fmaf(__int_as_float(q.y), h1[(size_t)q.x * 64 + lane], acc0);
    }

    float r = fmaxf(dn * ((acc0 + acc1) + dn * self) + bias, 0.f);

    // fused GEMM2: 8 wave-wide butterfly reductions
    float keep = 0.f;
#pragma unroll
    for (int c = 0; c < 8; ++c) {
        float s = r * w2r[c];
#pragma unroll
        for (int k = 1; k < 64; k <<= 1) s += __shfl_xor(s, k, 64);
        keep = ((lane & 7) == c) ? s : keep;
    }
    if (lane < 8) h2[(size_t)n * 8 + lane] = keep;
}

// ---------------- agg2: out = dinv[n]*(sum w_s*h2[s] + dinv[n]*h2[n]) + b2
// one wave per node: 8 neighbor slots x 8 cols, butterfly reduce.

__global__ __launch_bounds__(256) void k_agg2(const float* __restrict__ h2,
                                              const int* __restrict__ rowptr,
                                              const int2* __restrict__ csr_sw,
                                              const float* __restrict__ dinv,
                                              const float* __restrict__ b2,
                                              float* __restrict__ out, int N) {
    int wid = threadIdx.x >> 6;
    int lane = threadIdx.x & 63;
    int n = blockIdx.x * 4 + wid;
    if (n >= N) return;
    int start = rowptr[n];
    int cnt = rowptr[n + 1] - start;
    int c = lane & 7;
    int ii = lane >> 3;

    float a0 = 0.f, a1 = 0.f;
    int i = ii;
    for (; i + 8 < cnt; i += 16) {
        int2 q0 = csr_sw[start + i];
        int2 q1 = csr_sw[start + i + 8];
        float v0 = h2[(size_t)q0.x * 8 + c];
        float v1 = h2[(size_t)q1.x * 8 + c];
        a0 = fmaf(__int_as_float(q0.y), v0, a0);
        a1 = fmaf(__int_as_float(q1.y), v1, a1);
    }
    if (i < cnt) {
        int2 q = csr_sw[start + i];
        a0 = fmaf(__int_as_float(q.y), h2[(size_t)q.x * 8 + c], a0);
    }
    float acc = a0 + a1;
    acc += __shfl_xor(acc, 8, 64);
    acc += __shfl_xor(acc, 16, 64);
    acc += __shfl_xor(acc, 32, 64);

    if (lane < 8) {
        float dn = dinv[n];
        out[(size_t)n * 8 + lane] =
            dn * (acc + dn * h2[(size_t)n * 8 + lane]) + b2[lane];
    }
}

// ---------------- host launcher ----------------

extern "C" void kernel_launch(void* const* d_in, const int* in_sizes, int n_in,
                              void* d_out, int out_size, void* d_ws, size_t ws_size,
                              hipStream_t stream) {
    const float* x  = (const float*)d_in[0];
    const int*   ei = (const int*)d_in[1];
    const float* W1 = (const float*)d_in[2];
    const float* b1 = (const float*)d_in[3];
    const float* W2 = (const float*)d_in[4];
    const float* b2 = (const float*)d_in[5];
    float* out = (float*)d_out;

    const int H   = in_sizes[3];            // 64
    const int FIN = in_sizes[2] / H;        // 512
    const int N   = in_sizes[0] / FIN;      // 100000
    const int E   = in_sizes[1] / 2;        // 3200000
    const int* srcA = ei;
    const int* dstA = ei + E;

    char* ws = (char*)d_ws;
    size_t off = 0;
    auto alloc = [&](size_t bytes) -> void* {
        void* p = ws + off;
        off += (bytes + 255) & ~(size_t)255;
        return p;
    };
    int*   deg     = (int*)alloc((size_t)N * 4);
    float* dinv    = (float*)alloc((size_t)N * 4);
    int*   rowptr  = (int*)alloc((size_t)(N + 1) * 4);
    int*   cursor  = (int*)alloc((size_t)N * 4);
    int*   bsum    = (int*)alloc(4096);
    int2*  csr_sw  = (int2*)alloc((size_t)E * 8);
    float* h1      = (float*)alloc((size_t)N * 64 * 4);
    float* h2      = (float*)alloc((size_t)N * 8 * 4);
    (void)ws_size; (void)n_in; (void)out_size;

    int nb = (N + 255) / 256;    // scan blocks (391)

    k_zero   <<<nb, 256, 0, stream>>>(deg, N);
    k_deg    <<<(E + 255) / 256, 256, 0, stream>>>(dstA, deg, E);
    k_scan1  <<<nb, 256, 0, stream>>>(deg, rowptr, bsum, N);
    k_scan2  <<<1, 512, 0, stream>>>(bsum, nb);
    k_scan3  <<<nb, 256, 0, stream>>>(rowptr, bsum, cursor, deg, dinv, N, E);
    k_scatter<<<(E + 255) / 256, 256, 0, stream>>>(srcA, dstA, rowptr, cursor, dinv, csr_sw, E);
    k_gemm1  <<<(N + 63) / 64, 256, 0, stream>>>(x, W1, h1, N);
    k_agg1   <<<(N + 3) / 4, 256, 0, stream>>>(h1, rowptr, csr_sw, dinv, b1, W2, h2, N);
    k_agg2   <<<(N + 3) / 4, 256, 0, stream>>>(h2, rowptr, csr_sw, dinv, b2, out, N);
}

// Round 3
// 696.265 us; speedup vs baseline: 1.2170x; 1.0862x over previous
//
#include <hip/hip_runtime.h>
#include <cstdint>
#include <cstddef>

// ---------------- small utility kernels ----------------

__global__ void k_zero(int* __restrict__ p, int n) {
    int i = blockIdx.x * blockDim.x + threadIdx.x;
    if (i < n) p[i] = 0;
}

// degree count; the returned old value IS this edge's intra-row slot (rank).
// Storing it lets the scatter pass run with ZERO atomics.
__global__ void k_deg(const int* __restrict__ dst, int* __restrict__ deg,
                      int* __restrict__ rank, int E) {
    int e = blockIdx.x * blockDim.x + threadIdx.x;
    if (e < E) rank[e] = atomicAdd(&deg[dst[e]], 1);
}

// ---------------- exclusive scan (3 kernels) ----------------

__global__ void k_scan1(const int* __restrict__ deg, int* __restrict__ rowptr,
                        int* __restrict__ bsum, int N) {
    __shared__ int s[256];
    int t = threadIdx.x;
    int i = blockIdx.x * 256 + t;
    int v = (i < N) ? deg[i] : 0;
    s[t] = v;
    __syncthreads();
    for (int off = 1; off < 256; off <<= 1) {
        int add = (t >= off) ? s[t - off] : 0;
        __syncthreads();
        s[t] += add;
        __syncthreads();
    }
    if (i < N) rowptr[i] = s[t] - v;           // exclusive within block
    if (t == 255) bsum[blockIdx.x] = s[255];   // block total
}

__global__ void k_scan2(int* __restrict__ bsum, int nb) {
    __shared__ int s[512];
    int t = threadIdx.x;
    int v = (t < nb) ? bsum[t] : 0;
    s[t] = v;
    __syncthreads();
    for (int off = 1; off < 512; off <<= 1) {
        int add = (t >= off) ? s[t - off] : 0;
        __syncthreads();
        s[t] += add;
        __syncthreads();
    }
    if (t < nb) bsum[t] = s[t] - v;            // exclusive block offsets
}

// scan3 + dinv fused
__global__ void k_scan3(int* __restrict__ rowptr, const int* __restrict__ bsum,
                        const int* __restrict__ deg, float* __restrict__ dinv,
                        int N, int E) {
    int i = blockIdx.x * 256 + threadIdx.x;
    if (i < N) {
        rowptr[i] += bsum[blockIdx.x];
        dinv[i] = rsqrtf((float)(deg[i] + 1));   // +1 = self-loop
    }
    if (i == 0) rowptr[N] = E;
}

// atomic-free scatter: slot = rowptr[dst] + rank (precomputed in k_deg).
// Stores (src, dinv[src]) so the agg kernels never gather dinv at random.
__global__ void k_scatter(const int* __restrict__ src, const int* __restrict__ dst,
                          const int* __restrict__ rank, const int* __restrict__ rowptr,
                          const float* __restrict__ dinv, int2* __restrict__ csr_sw,
                          int E) {
    int e = blockIdx.x * blockDim.x + threadIdx.x;
    if (e < E) {
        int d = dst[e];
        int s = src[e];
        int2 q;
        q.x = s;
        q.y = __float_as_int(dinv[s]);
        csr_sw[rowptr[d] + rank[e]] = q;
    }
}

// ---------------- GEMM1: h1[N,64] = x[N,512] @ W1[512,64] ----------------
// 64 rows x 64 cols per block, 256 threads, 4x4 micro-tile, K-chunks of 32.

__global__ __launch_bounds__(256) void k_gemm1(const float* __restrict__ x,
                                               const float* __restrict__ W1,
                                               float* __restrict__ h1, int N) {
    __shared__ float xsT[32][68];   // [kk][row], stride 68 keeps float4 aligned
    __shared__ float ws[32][64];    // [kk][col]
    int t = threadIdx.x;
    int tc = t & 15;        // col group (4 cols)
    int tr = t >> 4;        // row group (4 rows)
    int row0 = blockIdx.x * 64;

    float acc[4][4] = {{0.f}};

    int lr  = t >> 2;        // staging row 0..63
    int lkq = (t & 3) * 8;   // staging k offset (8 floats)

    for (int k0 = 0; k0 < 512; k0 += 32) {
        {
            int gr = row0 + lr;
            float4 v0 = {0.f, 0.f, 0.f, 0.f}, v1 = {0.f, 0.f, 0.f, 0.f};
            if (gr < N) {
                const float* p = x + (size_t)gr * 512 + k0 + lkq;
                v0 = *(const float4*)p;
                v1 = *(const float4*)(p + 4);
            }
            xsT[lkq + 0][lr] = v0.x; xsT[lkq + 1][lr] = v0.y;
            xsT[lkq + 2][lr] = v0.z; xsT[lkq + 3][lr] = v0.w;
            xsT[lkq + 4][lr] = v1.x; xsT[lkq + 5][lr] = v1.y;
            xsT[lkq + 6][lr] = v1.z; xsT[lkq + 7][lr] = v1.w;
        }
        {
            const float* p = W1 + (size_t)k0 * 64 + t * 8;
            float4 v0 = *(const float4*)p;
            float4 v1 = *(const float4*)(p + 4);
            int kk = (t * 8) >> 6;
            int cc = (t * 8) & 63;
            *(float4*)&ws[kk][cc]     = v0;
            *(float4*)&ws[kk][cc + 4] = v1;
        }
        __syncthreads();

#pragma unroll
        for (int kk = 0; kk < 32; ++kk) {
            float4 a = *(const float4*)&xsT[kk][tr * 4];
            float4 b = *(const float4*)&ws[kk][tc * 4];
            acc[0][0] += a.x * b.x; acc[0][1] += a.x * b.y;
            acc[0][2] += a.x * b.z; acc[0][3] += a.x * b.w;
            acc[1][0] += a.y * b.x; acc[1][1] += a.y * b.y;
            acc[1][2] += a.y * b.z; acc[1][3] += a.y * b.w;
            acc[2][0] += a.z * b.x; acc[2][1] += a.z * b.y;
            acc[2][2] += a.z * b.z; acc[2][3] += a.z * b.w;
            acc[3][0] += a.w * b.x; acc[3][1] += a.w * b.y;
            acc[3][2] += a.w * b.z; acc[3][3] += a.w * b.w;
        }
        __syncthreads();
    }

#pragma unroll
    for (int r = 0; r < 4; ++r) {
        int gr = row0 + tr * 4 + r;
        if (gr < N) {
            float4 v = {acc[r][0], acc[r][1], acc[r][2], acc[r][3]};
            *(float4*)&h1[(size_t)gr * 64 + tc * 4] = v;
        }
    }
}

// ---------------- agg1 + GEMM2 fused ----------------
// one wave per node, lane = column (H=64).
// r = relu(dinv[n]*(sum_s w_s*h1[s] + dinv[n]*h1[n]) + b1)   (in regs, 1/lane)
// h2[n,c] = sum_k r[k]*W2[k,c]  via 8 butterfly reductions, compile-time select.

__global__ __launch_bounds__(256) void k_agg1(const float* __restrict__ h1,
                                              const int* __restrict__ rowptr,
                                              const int2* __restrict__ csr_sw,
                                              const float* __restrict__ dinv,
                                              const float* __restrict__ b1,
                                              const float* __restrict__ W2,
                                              float* __restrict__ h2, int N) {
    int wid = threadIdx.x >> 6;
    int lane = threadIdx.x & 63;
    int n = blockIdx.x * 4 + wid;
    if (n >= N) return;

    // hoisted loads (overlap with neighbor gathers)
    float w2r[8];
#pragma unroll
    for (int c = 0; c < 8; ++c) w2r[c] = W2[lane * 8 + c];
    float bias = b1[lane];
    float dn   = dinv[n];
    float self = h1[(size_t)n * 64 + lane];

    int start = __builtin_amdgcn_readfirstlane(rowptr[n]);
    int cnt   = __builtin_amdgcn_readfirstlane(rowptr[n + 1]) - start;
    const int2* qp = csr_sw + start;

    float acc0 = 0.f, acc1 = 0.f;
    int i = 0;
    for (; i + 8 <= cnt; i += 8) {
        int2 q0 = qp[i + 0]; int2 q1 = qp[i + 1];
        int2 q2 = qp[i + 2]; int2 q3 = qp[i + 3];
        int2 q4 = qp[i + 4]; int2 q5 = qp[i + 5];
        int2 q6 = qp[i + 6]; int2 q7 = qp[i + 7];
        float v0 = h1[(size_t)q0.x * 64 + lane];
        float v1 = h1[(size_t)q1.x * 64 + lane];
        float v2 = h1[(size_t)q2.x * 64 + lane];
        float v3 = h1[(size_t)q3.x * 64 + lane];
        float v4 = h1[(size_t)q4.x * 64 + lane];
        float v5 = h1[(size_t)q5.x * 64 + lane];
        float v6 = h1[(size_t)q6.x * 64 + lane];
        float v7 = h1[(size_t)q7.x * 64 + lane];
        acc0 = fmaf(__int_as_float(q0.y), v0, acc0);
        acc1 = fmaf(__int_as_float(q1.y), v1, acc1);
        acc0 = fmaf(__int_as_float(q2.y), v2, acc0);
        acc1 = fmaf(__int_as_float(q3.y), v3, acc1);
        acc0 = fmaf(__int_as_float(q4.y), v4, acc0);
        acc1 = fmaf(__int_as_float(q5.y), v5, acc1);
        acc0 = fmaf(__int_as_float(q6.y), v6, acc0);
        acc1 = fmaf(__int_as_float(q7.y), v7, acc1);
    }
    for (; i < cnt; ++i) {
        int2 q = qp[i];
        acc0 = fmaf(__int_as_float(q.y), h1[(size_t)q.x * 64 + lane], acc0);
    }

    float r = fmaxf(dn * ((acc0 + acc1) + dn * self) + bias, 0.f);

    // fused GEMM2: 8 wave-wide butterfly reductions
    float keep = 0.f;
#pragma unroll
    for (int c = 0; c < 8; ++c) {
        float s = r * w2r[c];
#pragma unroll
        for (int k = 1; k < 64; k <<= 1) s += __shfl_xor(s, k, 64);
        keep = ((lane & 7) == c) ? s : keep;
    }
    if (lane < 8) h2[(size_t)n * 8 + lane] = keep;
}

// ---------------- agg2: out = dinv[n]*(sum w_s*h2[s] + dinv[n]*h2[n]) + b2
// one wave per node: 8 neighbor slots x 8 cols, butterfly reduce.

__global__ __launch_bounds__(256) void k_agg2(const float* __restrict__ h2,
                                              const int* __restrict__ rowptr,
                                              const int2* __restrict__ csr_sw,
                                              const float* __restrict__ dinv,
                                              const float* __restrict__ b2,
                                              float* __restrict__ out, int N) {
    int wid = threadIdx.x >> 6;
    int lane = threadIdx.x & 63;
    int n = blockIdx.x * 4 + wid;
    if (n >= N) return;
    int start = rowptr[n];
    int cnt = rowptr[n + 1] - start;
    int c = lane & 7;
    int ii = lane >> 3;

    float a0 = 0.f, a1 = 0.f;
    int i = ii;
    for (; i + 8 < cnt; i += 16) {
        int2 q0 = csr_sw[start + i];
        int2 q1 = csr_sw[start + i + 8];
        float v0 = h2[(size_t)q0.x * 8 + c];
        float v1 = h2[(size_t)q1.x * 8 + c];
        a0 = fmaf(__int_as_float(q0.y), v0, a0);
        a1 = fmaf(__int_as_float(q1.y), v1, a1);
    }
    if (i < cnt) {
        int2 q = csr_sw[start + i];
        a0 = fmaf(__int_as_float(q.y), h2[(size_t)q.x * 8 + c], a0);
    }
    float acc = a0 + a1;
    acc += __shfl_xor(acc, 8, 64);
    acc += __shfl_xor(acc, 16, 64);
    acc += __shfl_xor(acc, 32, 64);

    if (lane < 8) {
        float dn = dinv[n];
        out[(size_t)n * 8 + lane] =
            dn * (acc + dn * h2[(size_t)n * 8 + lane]) + b2[lane];
    }
}

// ---------------- host launcher ----------------

extern "C" void kernel_launch(void* const* d_in, const int* in_sizes, int n_in,
                              void* d_out, int out_size, void* d_ws, size_t ws_size,
                              hipStream_t stream) {
    const float* x  = (const float*)d_in[0];
    const int*   ei = (const int*)d_in[1];
    const float* W1 = (const float*)d_in[2];
    const float* b1 = (const float*)d_in[3];
    const float* W2 = (const float*)d_in[4];
    const float* b2 = (const float*)d_in[5];
    float* out = (float*)d_out;

    const int H   = in_sizes[3];            // 64
    const int FIN = in_sizes[2] / H;        // 512
    const int N   = in_sizes[0] / FIN;      // 100000
    const int E   = in_sizes[1] / 2;        // 3200000
    const int* srcA = ei;
    const int* dstA = ei + E;

    char* ws = (char*)d_ws;
    size_t off = 0;
    auto alloc = [&](size_t bytes) -> void* {
        void* p = ws + off;
        off += (bytes + 255) & ~(size_t)255;
        return p;
    };
    int*   deg     = (int*)alloc((size_t)N * 4);
    float* dinv    = (float*)alloc((size_t)N * 4);
    int*   rowptr  = (int*)alloc((size_t)(N + 1) * 4);
    int*   rank    = (int*)alloc((size_t)E * 4);
    int*   bsum    = (int*)alloc(4096);
    int2*  csr_sw  = (int2*)alloc((size_t)E * 8);
    float* h1      = (float*)alloc((size_t)N * 64 * 4);
    float* h2      = (float*)alloc((size_t)N * 8 * 4);
    (void)ws_size; (void)n_in; (void)out_size;

    int nb = (N + 255) / 256;    // scan blocks (391)

    k_zero   <<<nb, 256, 0, stream>>>(deg, N);
    k_deg    <<<(E + 255) / 256, 256, 0, stream>>>(dstA, deg, rank, E);
    k_scan1  <<<nb, 256, 0, stream>>>(deg, rowptr, bsum, N);
    k_scan2  <<<1, 512, 0, stream>>>(bsum, nb);
    k_scan3  <<<nb, 256, 0, stream>>>(rowptr, bsum, deg, dinv, N, E);
    k_scatter<<<(E + 255) / 256, 256, 0, stream>>>(srcA, dstA, rank, rowptr, dinv, csr_sw, E);
    k_gemm1  <<<(N + 63) / 64, 256, 0, stream>>>(x, W1, h1, N);
    k_agg1   <<<(N + 3) / 4, 256, 0, stream>>>(h1, rowptr, csr_sw, dinv, b1, W2, h2, N);
    k_agg2   <<<(N + 3) / 4, 256, 0, stream>>>(h2, rowptr, csr_sw, dinv, b2, out, N);
}